// Round 17
// baseline (102.058 us; speedup 1.0000x reference)
//
#include <hip/hip_runtime.h>
#include <cstddef>

#define HD 8
#define C2 16
#define HH 28
#define WW 28
#define BB 16
#define SP (HH*WW)           // 784
#define FEAT (HD*SP)         // 6272
#define FEAT2 (C2*SP)        // 12544

#define TILE_ROWS 2
#define NT (HH/TILE_ROWS)    // 14
#define NBLK (BB*NT)         // 224 blocks, one per (batch, row-tile)
#define NTHR 1024            // 16 waves -> 4 waves/SIMD; VGPR cap 128 (measured
                             // sufficient for this cell form: round 14, 128 VGPR, no spill)

// LDS slab row extents (bases tied to r0)
#define X0_R 18   // x0  rows [r0-8, r0+9]
#define H00_R 14  // h00 rows [r0-6, r0+7]
#define H10_R 10  // h10 rows [r0-4, r0+5]
#define H11_R 6   // h11 rows [r0-2, r0+3]

__device__ __forceinline__ float sigf(float x) { return 1.0f / (1.0f + expf(-x)); }

union F4 { float4 v; float f[4]; };

struct SM {
    float gwt[C2*9][16];               // transposed gate weights [ic*9+k][oc]
    float cwt[C2*9][8];                // transposed cand weights [ic*9+k][oc]
    float gb[C2];
    float cb[HD];
    float hc1[HD];
    float hc2[HD];
    float comb[C2][18][32];            // A-phase out, rows [ca-2, ca+M+1]
    union {
        float rh[HD][16][32];          // B-phase r*h, rows [ca-1, ca+M]
        float s_in[3][TILE_ROWS+18][32]; // raw input rows r0-9..r0+10 (staging)
    } u;
    float su[HD][14][32];              // sig(u-conv), rows [ca, ca+M-1]
    float x0e[HD][X0_R][32];
    float h00e[HD][H00_R][32];
    float h10e[HD][H10_R][32];
    float h11e[HD][H11_R][32];
};  // ~128 KB

// Grid barrier (FALLBACK PATH ONLY — never executed when sweep-0 node1/2 constants are 0).
// Measured: an in-kernel grid barrier costs ~60-70us on MI355X regardless of
// design (rounds 4-6, 14). Keep ALL happy-path sync at kernel boundaries.
__device__ __forceinline__ void gbar(unsigned* arrive, unsigned* release,
                                     int blk, unsigned ep) {
    __syncthreads();
    __threadfence();
    if (threadIdx.x == 0)
        __hip_atomic_store(&arrive[(size_t)blk * 16], ep,
                           __ATOMIC_RELEASE, __HIP_MEMORY_SCOPE_AGENT);
    if (blk == 0) {
        int t = threadIdx.x;
        if (t < NBLK) {
            while (__hip_atomic_load(&arrive[(size_t)t * 16],
                                     __ATOMIC_RELAXED, __HIP_MEMORY_SCOPE_AGENT) < ep)
                __builtin_amdgcn_s_sleep(32);
        }
        __syncthreads();
        if (t < NBLK)
            __hip_atomic_store(&release[(size_t)t * 16], ep,
                               __ATOMIC_RELEASE, __HIP_MEMORY_SCOPE_AGENT);
    } else {
        if (threadIdx.x == 0) {
            while (__hip_atomic_load(&release[(size_t)blk * 16],
                                     __ATOMIC_RELAXED, __HIP_MEMORY_SCOPE_AGENT) < ep)
                __builtin_amdgcn_s_sleep(32);
        }
    }
    __threadfence();
    __syncthreads();
}

// Stage node-n weights TRANSPOSED: gwt[ic*9+k][oc], cwt[ic*9+k][oc].
__device__ __forceinline__ void stage_node(SM& sm, int tid, int n,
                           const float* gates_w, const float* gates_b,
                           const float* can_w, const float* can_b) {
    for (int i = tid; i < C2*C2*9; i += NTHR) {
        int oc = i & 15, r = i >> 4;                   // r = ic*9+k
        sm.gwt[r][oc] = gates_w[n*C2*C2*9 + oc*C2*9 + r];
    }
    for (int i = tid; i < C2*9*8; i += NTHR) {
        int oc = i & 7, r = i >> 3;
        sm.cwt[r][oc] = can_w[n*HD*C2*9 + oc*C2*9 + r];
    }
    if (tid < C2) sm.gb[tid] = gates_b[n*C2 + tid];
    if (tid < HD) sm.cb[tid] = can_b[n*HD + tid];
    // consumer phase's preceding __syncthreads covers these writes
}

template<int XS>
__device__ __forceinline__ const float* xrow(SM& sm, int c, int ridx) {
    if constexpr (XS == 0) return &sm.x0e[c][ridx][0];
    else if constexpr (XS == 1) return &sm.h10e[c][ridx][0];
    else return &sm.h11e[c][ridx][0];
}

// Full ConvGRU cell in LDS. M compile-time.
// XS: x slab (0=x0e,1=h10e,2=h11e); HS: h (0=zero,1=h00e,2=hc1,3=hc2);
// OS: out (0=h00e,1=h10e,2=h11e,3=global h12g).
// HS==0 elision: comb[8..15]==0, r*h==0 -> no rh phase, 8-channel convs.
// NOTE: this exact cell form (merged B, su in LDS, 1-col/4-oc items) is the
// best-measured variant (rounds 12/15/16); rounds 13/14 variants regressed.
template<int M, int XS, int HS, int OS>
__device__ void cell(SM& sm, int tid, int bi, int r0, float xs,
                     const float* __restrict__ td, float* __restrict__ h12g) {
    constexpr int R1 = M + 4, R2 = M + 2;
    constexpr int NIC = (HS == 0) ? HD : C2;
    const int ca    = (OS == 0) ? r0-6 : (OS == 1) ? r0-4 : (OS == 2) ? r0-2 : r0;
    const int xbase = (XS == 0) ? r0-8 : (XS == 1) ? r0-4 : r0-2;
    const int hbase = r0 - 6;                          // HS==1 only

    // ---- A: comb = (c<8 ? xs*x : h) * sig(td), float4 over cols ----
    for (int i = tid; i < NIC*R1*8; i += NTHR) {
        int ci4 = i & 7, rr = (i >> 3) % R1, c = i / (8*R1);
        int row = ca - 2 + rr;
        F4 v; v.f[0] = v.f[1] = v.f[2] = v.f[3] = 0.0f;
        if (row >= 0 && row < HH) {
            F4 base;
            if (c < HD) {
                base.v = *(const float4*)(xrow<XS>(sm, c, row - xbase) + ci4*4);
                #pragma unroll
                for (int e = 0; e < 4; ++e) base.f[e] *= xs;
            } else {
                if constexpr (HS == 1)
                    base.v = *(const float4*)(&sm.h00e[c-HD][row - hbase][ci4*4]);
                else if constexpr (HS == 2) {
                    float h = sm.hc1[c-HD];
                    base.f[0] = base.f[1] = base.f[2] = base.f[3] = h;
                } else {
                    float h = sm.hc2[c-HD];
                    base.f[0] = base.f[1] = base.f[2] = base.f[3] = h;
                }
            }
            const float* tdr = td + c*SP + row*WW;
            #pragma unroll
            for (int e = 0; e < 4; ++e) {
                int col = ci4*4 + e - 2;
                if (col >= 0 && col < WW)
                    v.f[e] = base.f[e] * sigf(tdr[col]);
            }
        }
        *(float4*)&sm.comb[c][rr][ci4*4] = v.v;
    }
    __syncthreads();

    // ---- B: rh rows [ca-1,ca+M] (HS!=0) MERGED WITH u-conv -> su rows [ca,ca+M-1] ----
    constexpr int itemsU = 2*M*32;
    if constexpr (HS != 0) {
        constexpr int itemsB = 2*R2*32;
        for (int i = tid; i < itemsB + itemsU; i += NTHR) {
            if (i < itemsB) {
                int ci = i & 31, rr = (i >> 5) % R2, g = i / (32*R2);
                int row = ca - 1 + rr, col = ci - 2;
                bool inb = (col >= 0 && col < WW && row >= 0 && row < HH);
                float a0 = sm.gb[g*4+0], a1 = sm.gb[g*4+1],
                      a2 = sm.gb[g*4+2], a3 = sm.gb[g*4+3];
                if (inb) {
                    #pragma unroll 2
                    for (int ic = 0; ic < C2; ++ic) {
                        const float* wb = &sm.gwt[ic*9][g*4];
                        #pragma unroll
                        for (int dy = 0; dy < 3; ++dy)
                            #pragma unroll
                            for (int dx = 0; dx < 3; ++dx) {
                                float cvv = sm.comb[ic][rr+dy][ci-1+dx];
                                F4 w; w.v = *(const float4*)(wb + (dy*3+dx)*16);
                                a0 += cvv*w.f[0]; a1 += cvv*w.f[1];
                                a2 += cvv*w.f[2]; a3 += cvv*w.f[3];
                            }
                    }
                }
                float av[4] = {a0, a1, a2, a3};
                #pragma unroll
                for (int o = 0; o < 4; ++o) {
                    int c = g*4 + o;
                    float v = 0.0f;
                    if (inb) {
                        float hv;
                        if constexpr (HS == 1) hv = sm.h00e[c][row - hbase][ci];
                        else if constexpr (HS == 2) hv = sm.hc1[c];
                        else hv = sm.hc2[c];
                        v = sigf(av[o]) * hv;
                    }
                    sm.u.rh[c][rr][ci] = v;
                }
            } else {
                int j = i - itemsB;
                int ci = j & 31, rr = (j >> 5) % M, g = j / (32*M);
                int row = ca + rr, col = ci - 2;
                bool inb = (col >= 0 && col < WW && row >= 0 && row < HH);
                float a0 = sm.gb[HD+g*4+0], a1 = sm.gb[HD+g*4+1],
                      a2 = sm.gb[HD+g*4+2], a3 = sm.gb[HD+g*4+3];
                if (inb) {
                    #pragma unroll 2
                    for (int ic = 0; ic < C2; ++ic) {
                        const float* wb = &sm.gwt[ic*9][HD + g*4];
                        #pragma unroll
                        for (int dy = 0; dy < 3; ++dy)
                            #pragma unroll
                            for (int dx = 0; dx < 3; ++dx) {
                                float cvv = sm.comb[ic][rr+1+dy][ci-1+dx];
                                F4 w; w.v = *(const float4*)(wb + (dy*3+dx)*16);
                                a0 += cvv*w.f[0]; a1 += cvv*w.f[1];
                                a2 += cvv*w.f[2]; a3 += cvv*w.f[3];
                            }
                    }
                }
                float av[4] = {a0, a1, a2, a3};
                #pragma unroll
                for (int o = 0; o < 4; ++o)
                    sm.su[g*4+o][rr][ci] = sigf(av[o]);
            }
        }
    } else {
        for (int i = tid; i < itemsU; i += NTHR) {
            int ci = i & 31, rr = (i >> 5) % M, g = i / (32*M);
            int row = ca + rr, col = ci - 2;
            bool inb = (col >= 0 && col < WW && row >= 0 && row < HH);
            float a0 = sm.gb[HD+g*4+0], a1 = sm.gb[HD+g*4+1],
                  a2 = sm.gb[HD+g*4+2], a3 = sm.gb[HD+g*4+3];
            if (inb) {
                #pragma unroll 2
                for (int ic = 0; ic < HD; ++ic) {
                    const float* wb = &sm.gwt[ic*9][HD + g*4];
                    #pragma unroll
                    for (int dy = 0; dy < 3; ++dy)
                        #pragma unroll
                        for (int dx = 0; dx < 3; ++dx) {
                            float cvv = sm.comb[ic][rr+1+dy][ci-1+dx];
                            F4 w; w.v = *(const float4*)(wb + (dy*3+dx)*16);
                            a0 += cvv*w.f[0]; a1 += cvv*w.f[1];
                            a2 += cvv*w.f[2]; a3 += cvv*w.f[3];
                        }
                }
            }
            float av[4] = {a0, a1, a2, a3};
            #pragma unroll
            for (int o = 0; o < 4; ++o)
                sm.su[g*4+o][rr][ci] = sigf(av[o]);
        }
    }
    __syncthreads();

    // ---- C: cand conv + blend, rows [ca, ca+M-1] ----
    for (int i = tid; i < 2*M*32; i += NTHR) {
        int ci = i & 31, rr = (i >> 5) % M, g = i / (32*M);
        int row = ca + rr, col = ci - 2;
        bool inb = (col >= 0 && col < WW && row >= 0 && row < HH);
        float a0 = sm.cb[g*4+0], a1 = sm.cb[g*4+1],
              a2 = sm.cb[g*4+2], a3 = sm.cb[g*4+3];
        if (inb) {
            #pragma unroll 2
            for (int ic = 0; ic < HD; ++ic) {
                const float* wb = &sm.cwt[ic*9][g*4];
                #pragma unroll
                for (int dy = 0; dy < 3; ++dy) {
                    const float* xr = xrow<XS>(sm, ic, (row - 1 + dy) - xbase);
                    #pragma unroll
                    for (int dx = 0; dx < 3; ++dx) {
                        float civ = xs * xr[ci-1+dx];
                        F4 w; w.v = *(const float4*)(wb + (dy*3+dx)*8);
                        a0 += civ*w.f[0]; a1 += civ*w.f[1];
                        a2 += civ*w.f[2]; a3 += civ*w.f[3];
                    }
                }
            }
            if constexpr (HS != 0) {
                #pragma unroll 2
                for (int ic = HD; ic < C2; ++ic) {
                    const float* wb = &sm.cwt[ic*9][g*4];
                    #pragma unroll
                    for (int dy = 0; dy < 3; ++dy)
                        #pragma unroll
                        for (int dx = 0; dx < 3; ++dx) {
                            float civ = sm.u.rh[ic-HD][rr+dy][ci-1+dx];
                            F4 w; w.v = *(const float4*)(wb + (dy*3+dx)*8);
                            a0 += civ*w.f[0]; a1 += civ*w.f[1];
                            a2 += civ*w.f[2]; a3 += civ*w.f[3];
                        }
                }
            }
        }
        float av[4] = {a0, a1, a2, a3};
        #pragma unroll
        for (int o = 0; o < 4; ++o) {
            int c = g*4 + o;
            float outv = 0.0f;
            if (inb) {
                float uu = sm.su[c][rr][ci];
                float cand = tanhf(av[o]);
                float hv;
                if constexpr (HS == 1) hv = sm.h00e[c][row - hbase][ci];
                else if constexpr (HS == 2) hv = sm.hc1[c];
                else if constexpr (HS == 3) hv = sm.hc2[c];
                else hv = 0.0f;
                outv = (1.0f - uu) * hv + uu * cand;
            }
            if constexpr (OS == 0) sm.h00e[c][row - (r0-6)][ci] = outv;
            else if constexpr (OS == 1) sm.h10e[c][row - (r0-4)][ci] = outv;
            else if constexpr (OS == 2) sm.h11e[c][row - (r0-2)][ci] = outv;
            else {
                if (inb)
                    h12g[((size_t)bi*HD + c)*SP + row*WW + col] = outv;
            }
        }
    }
    __syncthreads();
}

__global__ void init_kernel(unsigned* arrive, unsigned* release) {
    int t = threadIdx.x;
    for (int i = t; i < NBLK*16; i += 256) { arrive[i] = 0u; release[i] = 0u; }
}

// (1024, 4): 16 waves/block = 4 waves/SIMD; VGPR cap 128 — measured
// sufficient for this cell form (round 14: VGPR_Count=128, FETCH clean).
// LDS (128 KB) limits to 1 block/CU either way. If FETCH balloons, revert to 768.
__global__ __launch_bounds__(NTHR, 4)
void mega_kernel(const float* __restrict__ input_tensor, const float* __restrict__ topdown,
                 const float* __restrict__ icw, const float* __restrict__ icb,
                 const float* __restrict__ gates_w, const float* __restrict__ gates_b,
                 const float* __restrict__ can_w, const float* __restrict__ can_b,
                 const float* __restrict__ td_w0, const float* __restrict__ td_b0,
                 const float* __restrict__ td_w1, const float* __restrict__ td_b1,
                 float* __restrict__ h12g,
                 float* __restrict__ td0c, float* __restrict__ td1c,
                 unsigned* arrive, unsigned* release)
{
    const int tid = threadIdx.x;
    const int blk = blockIdx.x;
    const int bi  = blk / NT;
    const int r0  = (blk % NT) * TILE_ROWS;

    __shared__ SM sm;

    // Sweep-0 node1/2 outputs are per-channel constants (x=0,h=0 => comb==0).
    if (tid < HD) {
        sm.hc1[tid] = sigf(gates_b[1*C2 + HD + tid]) * tanhf(can_b[1*HD + tid]);
        sm.hc2[tid] = sigf(gates_b[2*C2 + HD + tid]) * tanhf(can_b[2*HD + tid]);
    }
    bool f0 = false, f1 = false;
    for (int c = 0; c < HD; ++c) {
        f0 |= (sigf(gates_b[1*C2 + HD + c]) * tanhf(can_b[1*HD + c])) != 0.0f;
        f1 |= (sigf(gates_b[2*C2 + HD + c]) * tanhf(can_b[2*HD + c])) != 0.0f;
    }

    // ---- stage raw input tile (rows r0-9..r0+10) + transposed input-conv weights ----
    for (int i = tid; i < 3*(TILE_ROWS+18)*32; i += NTHR) {
        int ci = i & 31, rr = (i >> 5) % (TILE_ROWS+18), c = i / (32*(TILE_ROWS+18));
        int row = r0 - 9 + rr, col = ci - 2;
        float v = 0.0f;
        if (row >= 0 && row < HH && col >= 0 && col < WW)
            v = input_tensor[((size_t)bi*3 + c)*SP + row*WW + col];
        sm.u.s_in[c][rr][ci] = v;
    }
    for (int i = tid; i < 3*9*8; i += NTHR) {          // icwt into gwt (borrow)
        int oc = i & 7, r = i >> 3;                    // r = ic*9+k < 27
        sm.gwt[r][oc] = icw[oc*27 + r];
    }
    if (tid < HD) sm.cb[tid] = icb[tid];               // borrow cb
    __syncthreads();

    // ---- x0e: input conv rows [r0-8, r0+9]; item=(row,col), 8 oc each ----
    for (int i = tid; i < X0_R*32; i += NTHR) {
        int ci = i & 31, rr = i >> 5;
        int row = r0 - 8 + rr, col = ci - 2;
        float acc[8];
        if (row >= 0 && row < HH && col >= 0 && col < WW) {
            #pragma unroll
            for (int o = 0; o < 8; ++o) acc[o] = sm.cb[o];
            for (int ic = 0; ic < 3; ++ic)
                #pragma unroll
                for (int dy = 0; dy < 3; ++dy)
                    #pragma unroll
                    for (int dx = 0; dx < 3; ++dx) {
                        float a = sm.u.s_in[ic][rr+dy][ci-1+dx];
                        F4 w0, w1;
                        w0.v = *(const float4*)&sm.gwt[ic*9+dy*3+dx][0];
                        w1.v = *(const float4*)&sm.gwt[ic*9+dy*3+dx][4];
                        acc[0] += a*w0.f[0]; acc[1] += a*w0.f[1];
                        acc[2] += a*w0.f[2]; acc[3] += a*w0.f[3];
                        acc[4] += a*w1.f[0]; acc[5] += a*w1.f[1];
                        acc[6] += a*w1.f[2]; acc[7] += a*w1.f[3];
                    }
        } else {
            #pragma unroll
            for (int o = 0; o < 8; ++o) acc[o] = 0.0f;
        }
        #pragma unroll
        for (int o = 0; o < 8; ++o) sm.x0e[o][rr][ci] = acc[o];
    }
    __syncthreads();   // x0e ready; gwt(icwt) reads done

    // ---- h00: sweep-0 node 0 (h=0), rows [r0-6, r0+7] ----
    stage_node(sm, tid, 0, gates_w, gates_b, can_w, can_b);   // no race: disjoint arrays
    cell<14, 0, 0, 0>(sm, tid, bi, r0, 1.0f, td_b0, nullptr);

    // ---- fallback: real td projections (h01/h02 constants nonzero) ----
    if (f0 | f1) {
        if (f0) {
            for (int j = blk*NTHR + tid; j < FEAT2; j += NBLK*NTHR) {
                float s = td_b0[j];
                const float* wr = td_w0 + (size_t)j * FEAT;
                for (int c = 0; c < HD; ++c) {
                    float hcv = sm.hc1[c];
                    if (hcv != 0.0f) {
                        float ss = 0.0f;
                        for (int p = 0; p < SP; ++p) ss += wr[c*SP + p];
                        s += 0.6f * hcv * ss;
                    }
                }
                td0c[j] = s;
            }
        }
        if (f1) {
            for (int j = blk*NTHR + tid; j < FEAT2; j += NBLK*NTHR) {
                float s = td_b1[j];
                const float* wr = td_w1 + (size_t)j * FEAT;
                for (int c = 0; c < HD; ++c) {
                    float hcv = sm.hc2[c];
                    if (hcv != 0.0f) {
                        float ss = 0.0f;
                        for (int p = 0; p < SP; ++p) ss += wr[c*SP + p];
                        s += 0.5f * hcv * ss;
                    }
                }
                td1c[j] = s;
            }
        }
        gbar(arrive, release, blk, 1u);   // uniform branch: all blocks take it
    }
    const float* td0v = f0 ? td0c : td_b0;
    const float* td1v = f1 ? td1c : td_b1;

    // ---- h10: sweep-1 node 0 (weights resident), rows [r0-4, r0+5] ----
    cell<10, 0, 1, 1>(sm, tid, bi, r0, 1.0f, td0v, nullptr);

    // ---- h11: sweep-1 node 1 (x=0.8*h10, h=hc1), rows [r0-2, r0+3] ----
    stage_node(sm, tid, 1, gates_w, gates_b, can_w, can_b);
    cell<6, 1, 2, 2>(sm, tid, bi, r0, 0.8f, td1v, nullptr);

    // ---- h12: sweep-1 node 2 (x=0.7*h11, h=hc2, td external), rows [r0, r0+1] ----
    stage_node(sm, tid, 2, gates_w, gates_b, can_w, can_b);
    cell<2, 2, 3, 3>(sm, tid, bi, r0, 0.7f, topdown + (size_t)bi*FEAT2, h12g);
}

// 512 threads: latency-bound on 2.5 MB weight reads -> 8 waves of
// outstanding loads. Each wave handles 2 batches; per-output k-order
// and shfl tree unchanged -> bit-exact.
__global__ __launch_bounds__(512)
void fc1_kernel(const float* __restrict__ in, const float* __restrict__ w,
                const float* __restrict__ b, float* __restrict__ out) {
    int j    = blockIdx.x;          // 0..99
    int wave = threadIdx.x >> 6;    // 0..7
    int lane = threadIdx.x & 63;
    float acc[2] = {0.f, 0.f};
    const float* wr = w + (size_t)j * FEAT;
    for (int k = lane; k < FEAT; k += 64) {
        float wv = wr[k];
        #pragma unroll
        for (int q = 0; q < 2; ++q) {
            float v = in[(size_t)(wave*2+q)*FEAT + k];
            acc[q] += fmaxf(v, 0.0f) * wv;
        }
    }
    #pragma unroll
    for (int off = 32; off > 0; off >>= 1)
        #pragma unroll
        for (int q = 0; q < 2; ++q)
            acc[q] += __shfl_down(acc[q], off);
    if (lane == 0) {
        #pragma unroll
        for (int q = 0; q < 2; ++q)
            out[(size_t)(wave*2+q)*100 + j] = acc[q] + b[j];
    }
}

__global__ __launch_bounds__(256)
void fc2_kernel(const float* __restrict__ p1, const float* __restrict__ w,
                const float* __restrict__ b, float* __restrict__ out) {
    int t = threadIdx.x;
    if (t >= BB*10) return;
    int bi = t / 10, j = t % 10;
    float acc = b[j];
    for (int k = 0; k < 100; ++k)
        acc += fmaxf(p1[bi*100 + k], 0.0f) * w[j*100 + k];
    out[bi*10 + j] = acc;
}

extern "C" void kernel_launch(void* const* d_in, const int* in_sizes, int n_in,
                              void* d_out, int out_size, void* d_ws, size_t ws_size,
                              hipStream_t stream) {
    const float* input_tensor = (const float*)d_in[0];
    const float* topdown      = (const float*)d_in[1];
    const float* icw  = (const float*)d_in[2];
    const float* icb  = (const float*)d_in[3];
    const float* gates_w = (const float*)d_in[4];
    const float* gates_b = (const float*)d_in[5];
    const float* can_w   = (const float*)d_in[6];
    const float* can_b   = (const float*)d_in[7];
    const float* td_w0 = (const float*)d_in[8];
    const float* td_b0 = (const float*)d_in[9];
    const float* td_w1 = (const float*)d_in[10];
    const float* td_b1 = (const float*)d_in[11];
    const float* fc1_w = (const float*)d_in[12];
    const float* fc1_b = (const float*)d_in[13];
    const float* fc2_w = (const float*)d_in[14];
    const float* fc2_b = (const float*)d_in[15];
    float* out = (float*)d_out;

    float* ws   = (float*)d_ws;
    float* h12g = ws;                       // 100352 f
    float* p1   = h12g + BB*HD*SP;          // 1600 f
    float* td0c = p1 + BB*100;              // 12544 f
    float* td1c = td0c + FEAT2;             // 12544 f
    unsigned* arrive  = (unsigned*)((char*)d_ws + (16u << 20));
    unsigned* release = arrive + NBLK*16;

    init_kernel<<<1, 256, 0, stream>>>(arrive, release);
    mega_kernel<<<NBLK, NTHR, 0, stream>>>(
        input_tensor, topdown, icw, icb, gates_w, gates_b, can_w, can_b,
        td_w0, td_b0, td_w1, td_b1,
        h12g, td0c, td1c, arrive, release);
    fc1_kernel<<<100, 512, 0, stream>>>(h12g, fc1_w, fc1_b, p1);
    fc2_kernel<<<1, 256, 0, stream>>>(p1, fc2_w, fc2_b, out);
}

// Round 18
// 94.529 us; speedup vs baseline: 1.0797x; 1.0797x over previous
//
#include <hip/hip_runtime.h>
#include <cstddef>

#define HD 8
#define C2 16
#define HH 28
#define WW 28
#define BB 16
#define SP (HH*WW)           // 784
#define FEAT (HD*SP)         // 6272
#define FEAT2 (C2*SP)        // 12544

#define TILE_ROWS 2
#define NT (HH/TILE_ROWS)    // 14
#define NBLK (BB*NT)         // 224 blocks, one per (batch, row-tile)
#define NTHR 768             // 12 waves -> 3 waves/SIMD (measured best, round 16)

// LDS slab row extents (bases tied to r0)
#define X0_R 18   // x0  rows [r0-8, r0+9]
#define H00_R 14  // h00 rows [r0-6, r0+7]
#define H10_R 10  // h10 rows [r0-4, r0+5]
#define H11_R 6   // h11 rows [r0-2, r0+3]

__device__ __forceinline__ float sigf(float x) { return 1.0f / (1.0f + expf(-x)); }

union F4 { float4 v; float f[4]; };

struct SM {
    float gwt[C2*9][16];               // transposed gate weights [ic*9+k][oc]
    float cwt[C2*9][8];                // transposed cand weights [ic*9+k][oc]
    float gb[C2];
    float cb[HD];
    float hc1[HD];
    float hc2[HD];
    float comb[C2][18][32];            // A-phase out; reused as fc1 scratch at tail
    union {
        float rh[HD][16][32];          // B-phase r*h, rows [ca-1, ca+M]
        float s_in[3][TILE_ROWS+18][32]; // raw input rows r0-9..r0+10 (staging)
    } u;
    float su[HD][14][32];              // sig(u-conv), rows [ca, ca+M-1]
    float x0e[HD][X0_R][32];
    float h00e[HD][H00_R][32];
    float h10e[HD][H10_R][32];
    float h11e[HD][H11_R][32];
};  // ~128 KB

// Grid barrier (FALLBACK PATH ONLY — never executed when sweep-0 node1/2 constants are 0).
// Measured: an in-kernel grid barrier costs ~60-70us on MI355X regardless of
// design (rounds 4-6, 14). Keep ALL happy-path sync at kernel boundaries.
__device__ __forceinline__ void gbar(unsigned* arrive, unsigned* release,
                                     int blk, unsigned ep) {
    __syncthreads();
    __threadfence();
    if (threadIdx.x == 0)
        __hip_atomic_store(&arrive[(size_t)blk * 16], ep,
                           __ATOMIC_RELEASE, __HIP_MEMORY_SCOPE_AGENT);
    if (blk == 0) {
        int t = threadIdx.x;
        if (t < NBLK) {
            while (__hip_atomic_load(&arrive[(size_t)t * 16],
                                     __ATOMIC_RELAXED, __HIP_MEMORY_SCOPE_AGENT) < ep)
                __builtin_amdgcn_s_sleep(32);
        }
        __syncthreads();
        if (t < NBLK)
            __hip_atomic_store(&release[(size_t)t * 16], ep,
                               __ATOMIC_RELEASE, __HIP_MEMORY_SCOPE_AGENT);
    } else {
        if (threadIdx.x == 0) {
            while (__hip_atomic_load(&release[(size_t)blk * 16],
                                     __ATOMIC_RELAXED, __HIP_MEMORY_SCOPE_AGENT) < ep)
                __builtin_amdgcn_s_sleep(32);
        }
    }
    __threadfence();
    __syncthreads();
}

// Stage node-n weights TRANSPOSED: gwt[ic*9+k][oc], cwt[ic*9+k][oc].
__device__ __forceinline__ void stage_node(SM& sm, int tid, int n,
                           const float* gates_w, const float* gates_b,
                           const float* can_w, const float* can_b) {
    for (int i = tid; i < C2*C2*9; i += NTHR) {
        int oc = i & 15, r = i >> 4;                   // r = ic*9+k
        sm.gwt[r][oc] = gates_w[n*C2*C2*9 + oc*C2*9 + r];
    }
    for (int i = tid; i < C2*9*8; i += NTHR) {
        int oc = i & 7, r = i >> 3;
        sm.cwt[r][oc] = can_w[n*HD*C2*9 + oc*C2*9 + r];
    }
    if (tid < C2) sm.gb[tid] = gates_b[n*C2 + tid];
    if (tid < HD) sm.cb[tid] = can_b[n*HD + tid];
    // consumer phase's preceding __syncthreads covers these writes
}

template<int XS>
__device__ __forceinline__ const float* xrow(SM& sm, int c, int ridx) {
    if constexpr (XS == 0) return &sm.x0e[c][ridx][0];
    else if constexpr (XS == 1) return &sm.h10e[c][ridx][0];
    else return &sm.h11e[c][ridx][0];
}

// Full ConvGRU cell in LDS. M compile-time.
// XS: x slab (0=x0e,1=h10e,2=h11e); HS: h (0=zero,1=h00e,2=hc1,3=hc2);
// OS: out (0=h00e,1=h10e,2=h11e,3=global h12g).
// HS==0 elision: comb[8..15]==0, r*h==0 -> no rh phase, 8-channel convs.
// NOTE: this exact cell form (merged B, su in LDS, 1-col/4-oc items) is the
// best-measured variant (rounds 12/15/16); rounds 13/14 variants regressed.
template<int M, int XS, int HS, int OS>
__device__ void cell(SM& sm, int tid, int bi, int r0, float xs,
                     const float* __restrict__ td, float* __restrict__ h12g) {
    constexpr int R1 = M + 4, R2 = M + 2;
    constexpr int NIC = (HS == 0) ? HD : C2;
    const int ca    = (OS == 0) ? r0-6 : (OS == 1) ? r0-4 : (OS == 2) ? r0-2 : r0;
    const int xbase = (XS == 0) ? r0-8 : (XS == 1) ? r0-4 : r0-2;
    const int hbase = r0 - 6;                          // HS==1 only

    // ---- A: comb = (c<8 ? xs*x : h) * sig(td), float4 over cols ----
    for (int i = tid; i < NIC*R1*8; i += NTHR) {
        int ci4 = i & 7, rr = (i >> 3) % R1, c = i / (8*R1);
        int row = ca - 2 + rr;
        F4 v; v.f[0] = v.f[1] = v.f[2] = v.f[3] = 0.0f;
        if (row >= 0 && row < HH) {
            F4 base;
            if (c < HD) {
                base.v = *(const float4*)(xrow<XS>(sm, c, row - xbase) + ci4*4);
                #pragma unroll
                for (int e = 0; e < 4; ++e) base.f[e] *= xs;
            } else {
                if constexpr (HS == 1)
                    base.v = *(const float4*)(&sm.h00e[c-HD][row - hbase][ci4*4]);
                else if constexpr (HS == 2) {
                    float h = sm.hc1[c-HD];
                    base.f[0] = base.f[1] = base.f[2] = base.f[3] = h;
                } else {
                    float h = sm.hc2[c-HD];
                    base.f[0] = base.f[1] = base.f[2] = base.f[3] = h;
                }
            }
            const float* tdr = td + c*SP + row*WW;
            #pragma unroll
            for (int e = 0; e < 4; ++e) {
                int col = ci4*4 + e - 2;
                if (col >= 0 && col < WW)
                    v.f[e] = base.f[e] * sigf(tdr[col]);
            }
        }
        *(float4*)&sm.comb[c][rr][ci4*4] = v.v;
    }
    __syncthreads();

    // ---- B: rh rows [ca-1,ca+M] (HS!=0) MERGED WITH u-conv -> su rows [ca,ca+M-1] ----
    constexpr int itemsU = 2*M*32;
    if constexpr (HS != 0) {
        constexpr int itemsB = 2*R2*32;
        for (int i = tid; i < itemsB + itemsU; i += NTHR) {
            if (i < itemsB) {
                int ci = i & 31, rr = (i >> 5) % R2, g = i / (32*R2);
                int row = ca - 1 + rr, col = ci - 2;
                bool inb = (col >= 0 && col < WW && row >= 0 && row < HH);
                float a0 = sm.gb[g*4+0], a1 = sm.gb[g*4+1],
                      a2 = sm.gb[g*4+2], a3 = sm.gb[g*4+3];
                if (inb) {
                    #pragma unroll 2
                    for (int ic = 0; ic < C2; ++ic) {
                        const float* wb = &sm.gwt[ic*9][g*4];
                        #pragma unroll
                        for (int dy = 0; dy < 3; ++dy)
                            #pragma unroll
                            for (int dx = 0; dx < 3; ++dx) {
                                float cvv = sm.comb[ic][rr+dy][ci-1+dx];
                                F4 w; w.v = *(const float4*)(wb + (dy*3+dx)*16);
                                a0 += cvv*w.f[0]; a1 += cvv*w.f[1];
                                a2 += cvv*w.f[2]; a3 += cvv*w.f[3];
                            }
                    }
                }
                float av[4] = {a0, a1, a2, a3};
                #pragma unroll
                for (int o = 0; o < 4; ++o) {
                    int c = g*4 + o;
                    float v = 0.0f;
                    if (inb) {
                        float hv;
                        if constexpr (HS == 1) hv = sm.h00e[c][row - hbase][ci];
                        else if constexpr (HS == 2) hv = sm.hc1[c];
                        else hv = sm.hc2[c];
                        v = sigf(av[o]) * hv;
                    }
                    sm.u.rh[c][rr][ci] = v;
                }
            } else {
                int j = i - itemsB;
                int ci = j & 31, rr = (j >> 5) % M, g = j / (32*M);
                int row = ca + rr, col = ci - 2;
                bool inb = (col >= 0 && col < WW && row >= 0 && row < HH);
                float a0 = sm.gb[HD+g*4+0], a1 = sm.gb[HD+g*4+1],
                      a2 = sm.gb[HD+g*4+2], a3 = sm.gb[HD+g*4+3];
                if (inb) {
                    #pragma unroll 2
                    for (int ic = 0; ic < C2; ++ic) {
                        const float* wb = &sm.gwt[ic*9][HD + g*4];
                        #pragma unroll
                        for (int dy = 0; dy < 3; ++dy)
                            #pragma unroll
                            for (int dx = 0; dx < 3; ++dx) {
                                float cvv = sm.comb[ic][rr+1+dy][ci-1+dx];
                                F4 w; w.v = *(const float4*)(wb + (dy*3+dx)*16);
                                a0 += cvv*w.f[0]; a1 += cvv*w.f[1];
                                a2 += cvv*w.f[2]; a3 += cvv*w.f[3];
                            }
                    }
                }
                float av[4] = {a0, a1, a2, a3};
                #pragma unroll
                for (int o = 0; o < 4; ++o)
                    sm.su[g*4+o][rr][ci] = sigf(av[o]);
            }
        }
    } else {
        for (int i = tid; i < itemsU; i += NTHR) {
            int ci = i & 31, rr = (i >> 5) % M, g = i / (32*M);
            int row = ca + rr, col = ci - 2;
            bool inb = (col >= 0 && col < WW && row >= 0 && row < HH);
            float a0 = sm.gb[HD+g*4+0], a1 = sm.gb[HD+g*4+1],
                  a2 = sm.gb[HD+g*4+2], a3 = sm.gb[HD+g*4+3];
            if (inb) {
                #pragma unroll 2
                for (int ic = 0; ic < HD; ++ic) {
                    const float* wb = &sm.gwt[ic*9][HD + g*4];
                    #pragma unroll
                    for (int dy = 0; dy < 3; ++dy)
                        #pragma unroll
                        for (int dx = 0; dx < 3; ++dx) {
                            float cvv = sm.comb[ic][rr+1+dy][ci-1+dx];
                            F4 w; w.v = *(const float4*)(wb + (dy*3+dx)*16);
                            a0 += cvv*w.f[0]; a1 += cvv*w.f[1];
                            a2 += cvv*w.f[2]; a3 += cvv*w.f[3];
                        }
                }
            }
            float av[4] = {a0, a1, a2, a3};
            #pragma unroll
            for (int o = 0; o < 4; ++o)
                sm.su[g*4+o][rr][ci] = sigf(av[o]);
        }
    }
    __syncthreads();

    // ---- C: cand conv + blend, rows [ca, ca+M-1] ----
    for (int i = tid; i < 2*M*32; i += NTHR) {
        int ci = i & 31, rr = (i >> 5) % M, g = i / (32*M);
        int row = ca + rr, col = ci - 2;
        bool inb = (col >= 0 && col < WW && row >= 0 && row < HH);
        float a0 = sm.cb[g*4+0], a1 = sm.cb[g*4+1],
              a2 = sm.cb[g*4+2], a3 = sm.cb[g*4+3];
        if (inb) {
            #pragma unroll 2
            for (int ic = 0; ic < HD; ++ic) {
                const float* wb = &sm.cwt[ic*9][g*4];
                #pragma unroll
                for (int dy = 0; dy < 3; ++dy) {
                    const float* xr = xrow<XS>(sm, ic, (row - 1 + dy) - xbase);
                    #pragma unroll
                    for (int dx = 0; dx < 3; ++dx) {
                        float civ = xs * xr[ci-1+dx];
                        F4 w; w.v = *(const float4*)(wb + (dy*3+dx)*8);
                        a0 += civ*w.f[0]; a1 += civ*w.f[1];
                        a2 += civ*w.f[2]; a3 += civ*w.f[3];
                    }
                }
            }
            if constexpr (HS != 0) {
                #pragma unroll 2
                for (int ic = HD; ic < C2; ++ic) {
                    const float* wb = &sm.cwt[ic*9][g*4];
                    #pragma unroll
                    for (int dy = 0; dy < 3; ++dy)
                        #pragma unroll
                        for (int dx = 0; dx < 3; ++dx) {
                            float civ = sm.u.rh[ic-HD][rr+dy][ci-1+dx];
                            F4 w; w.v = *(const float4*)(wb + (dy*3+dx)*8);
                            a0 += civ*w.f[0]; a1 += civ*w.f[1];
                            a2 += civ*w.f[2]; a3 += civ*w.f[3];
                        }
                }
            }
        }
        float av[4] = {a0, a1, a2, a3};
        #pragma unroll
        for (int o = 0; o < 4; ++o) {
            int c = g*4 + o;
            float outv = 0.0f;
            if (inb) {
                float uu = sm.su[c][rr][ci];
                float cand = tanhf(av[o]);
                float hv;
                if constexpr (HS == 1) hv = sm.h00e[c][row - hbase][ci];
                else if constexpr (HS == 2) hv = sm.hc1[c];
                else if constexpr (HS == 3) hv = sm.hc2[c];
                else hv = 0.0f;
                outv = (1.0f - uu) * hv + uu * cand;
            }
            if constexpr (OS == 0) sm.h00e[c][row - (r0-6)][ci] = outv;
            else if constexpr (OS == 1) sm.h10e[c][row - (r0-4)][ci] = outv;
            else if constexpr (OS == 2) sm.h11e[c][row - (r0-2)][ci] = outv;
            else {
                if (inb)
                    h12g[((size_t)bi*HD + c)*SP + row*WW + col] = outv;
            }
        }
    }
    __syncthreads();
}

__global__ void init_kernel(unsigned* arrive, unsigned* release) {
    int t = threadIdx.x;
    for (int i = t; i < NBLK*16; i += 256) { arrive[i] = 0u; release[i] = 0u; }
}

// (768, 3): 3 waves/SIMD (measured best); VGPR budget ~170/wave; LDS 128 KB
// -> 1 block/CU.
__global__ __launch_bounds__(NTHR, 3)
void mega_kernel(const float* __restrict__ input_tensor, const float* __restrict__ topdown,
                 const float* __restrict__ icw, const float* __restrict__ icb,
                 const float* __restrict__ gates_w, const float* __restrict__ gates_b,
                 const float* __restrict__ can_w, const float* __restrict__ can_b,
                 const float* __restrict__ td_w0, const float* __restrict__ td_b0,
                 const float* __restrict__ td_w1, const float* __restrict__ td_b1,
                 const float* __restrict__ fc1_w,
                 float* __restrict__ h12g, float* __restrict__ p1p,
                 float* __restrict__ td0c, float* __restrict__ td1c,
                 unsigned* arrive, unsigned* release)
{
    const int tid = threadIdx.x;
    const int blk = blockIdx.x;
    const int bi  = blk / NT;
    const int r0  = (blk % NT) * TILE_ROWS;

    __shared__ SM sm;

    // Sweep-0 node1/2 outputs are per-channel constants (x=0,h=0 => comb==0).
    if (tid < HD) {
        sm.hc1[tid] = sigf(gates_b[1*C2 + HD + tid]) * tanhf(can_b[1*HD + tid]);
        sm.hc2[tid] = sigf(gates_b[2*C2 + HD + tid]) * tanhf(can_b[2*HD + tid]);
    }
    bool f0 = false, f1 = false;
    for (int c = 0; c < HD; ++c) {
        f0 |= (sigf(gates_b[1*C2 + HD + c]) * tanhf(can_b[1*HD + c])) != 0.0f;
        f1 |= (sigf(gates_b[2*C2 + HD + c]) * tanhf(can_b[2*HD + c])) != 0.0f;
    }

    // ---- stage raw input tile (rows r0-9..r0+10) + transposed input-conv weights ----
    for (int i = tid; i < 3*(TILE_ROWS+18)*32; i += NTHR) {
        int ci = i & 31, rr = (i >> 5) % (TILE_ROWS+18), c = i / (32*(TILE_ROWS+18));
        int row = r0 - 9 + rr, col = ci - 2;
        float v = 0.0f;
        if (row >= 0 && row < HH && col >= 0 && col < WW)
            v = input_tensor[((size_t)bi*3 + c)*SP + row*WW + col];
        sm.u.s_in[c][rr][ci] = v;
    }
    for (int i = tid; i < 3*9*8; i += NTHR) {          // icwt into gwt (borrow)
        int oc = i & 7, r = i >> 3;                    // r = ic*9+k < 27
        sm.gwt[r][oc] = icw[oc*27 + r];
    }
    if (tid < HD) sm.cb[tid] = icb[tid];               // borrow cb
    __syncthreads();

    // ---- x0e: input conv rows [r0-8, r0+9]; item=(row,col), 8 oc each ----
    for (int i = tid; i < X0_R*32; i += NTHR) {
        int ci = i & 31, rr = i >> 5;
        int row = r0 - 8 + rr, col = ci - 2;
        float acc[8];
        if (row >= 0 && row < HH && col >= 0 && col < WW) {
            #pragma unroll
            for (int o = 0; o < 8; ++o) acc[o] = sm.cb[o];
            for (int ic = 0; ic < 3; ++ic)
                #pragma unroll
                for (int dy = 0; dy < 3; ++dy)
                    #pragma unroll
                    for (int dx = 0; dx < 3; ++dx) {
                        float a = sm.u.s_in[ic][rr+dy][ci-1+dx];
                        F4 w0, w1;
                        w0.v = *(const float4*)&sm.gwt[ic*9+dy*3+dx][0];
                        w1.v = *(const float4*)&sm.gwt[ic*9+dy*3+dx][4];
                        acc[0] += a*w0.f[0]; acc[1] += a*w0.f[1];
                        acc[2] += a*w0.f[2]; acc[3] += a*w0.f[3];
                        acc[4] += a*w1.f[0]; acc[5] += a*w1.f[1];
                        acc[6] += a*w1.f[2]; acc[7] += a*w1.f[3];
                    }
        } else {
            #pragma unroll
            for (int o = 0; o < 8; ++o) acc[o] = 0.0f;
        }
        #pragma unroll
        for (int o = 0; o < 8; ++o) sm.x0e[o][rr][ci] = acc[o];
    }
    __syncthreads();   // x0e ready; gwt(icwt) reads done

    // ---- h00: sweep-0 node 0 (h=0), rows [r0-6, r0+7] ----
    stage_node(sm, tid, 0, gates_w, gates_b, can_w, can_b);   // no race: disjoint arrays
    cell<14, 0, 0, 0>(sm, tid, bi, r0, 1.0f, td_b0, nullptr);

    // ---- fallback: real td projections (h01/h02 constants nonzero) ----
    if (f0 | f1) {
        if (f0) {
            for (int j = blk*NTHR + tid; j < FEAT2; j += NBLK*NTHR) {
                float s = td_b0[j];
                const float* wr = td_w0 + (size_t)j * FEAT;
                for (int c = 0; c < HD; ++c) {
                    float hcv = sm.hc1[c];
                    if (hcv != 0.0f) {
                        float ss = 0.0f;
                        for (int p = 0; p < SP; ++p) ss += wr[c*SP + p];
                        s += 0.6f * hcv * ss;
                    }
                }
                td0c[j] = s;
            }
        }
        if (f1) {
            for (int j = blk*NTHR + tid; j < FEAT2; j += NBLK*NTHR) {
                float s = td_b1[j];
                const float* wr = td_w1 + (size_t)j * FEAT;
                for (int c = 0; c < HD; ++c) {
                    float hcv = sm.hc2[c];
                    if (hcv != 0.0f) {
                        float ss = 0.0f;
                        for (int p = 0; p < SP; ++p) ss += wr[c*SP + p];
                        s += 0.5f * hcv * ss;
                    }
                }
                td1c[j] = s;
            }
        }
        gbar(arrive, release, blk, 1u);   // uniform branch: all blocks take it
    }
    const float* td0v = f0 ? td0c : td_b0;
    const float* td1v = f1 ? td1c : td_b1;

    // ---- h10: sweep-1 node 0 (weights resident), rows [r0-4, r0+5] ----
    cell<10, 0, 1, 1>(sm, tid, bi, r0, 1.0f, td0v, nullptr);

    // ---- h11: sweep-1 node 1 (x=0.8*h10, h=hc1), rows [r0-2, r0+3] ----
    stage_node(sm, tid, 1, gates_w, gates_b, can_w, can_b);
    cell<6, 1, 2, 2>(sm, tid, bi, r0, 0.8f, td1v, nullptr);

    // ---- h12: sweep-1 node 2 (x=0.7*h11, h=hc2, td external), rows [r0, r0+1] ----
    stage_node(sm, tid, 2, gates_w, gates_b, can_w, can_b);
    cell<2, 2, 3, 3>(sm, tid, bi, r0, 0.7f, topdown + (size_t)bi*FEAT2, h12g);

    // ---- fc1 partials (fused tail): this block owns batch bi's k-slice
    // rows r0..r0+1 (448 k's). No extra sync needed: we read only OUR OWN
    // h12 writes (drained by the cell's final __syncthreads, L2-coherent on
    // the same CU). Deterministic: fixed part decomposition + fixed sum order.
    {
        float* scratch = &sm.comb[0][0][0];   // comb free after last cell
        if (tid < 400) {
            int j = tid >> 2, p = tid & 3;    // j=0..99, 4 parts x 112 k's
            float acc = 0.0f;
            for (int s = 0; s < 112; ++s) {
                int kl  = p*112 + s;          // 0..447: c-major, row, col
                int c   = kl / 56;
                int rem = kl % 56;
                int rr  = rem / 28, col = rem % 28;
                int k   = c*SP + (r0 + rr)*WW + col;
                float v = h12g[(size_t)bi*FEAT + k];
                acc += fmaxf(v, 0.0f) * fc1_w[(size_t)j*FEAT + k];
            }
            scratch[j*4 + p] = acc;
        }
        __syncthreads();
        if (tid < 100) {
            float s = scratch[tid*4+0] + scratch[tid*4+1]
                    + scratch[tid*4+2] + scratch[tid*4+3];
            p1p[(size_t)blk*100 + tid] = s;
        }
    }
}

// Combine fc1 partials (fixed tile order) + bias + relu, then fc2. 1 block.
__global__ __launch_bounds__(1024)
void fc_tail_kernel(const float* __restrict__ p1p, const float* __restrict__ fc1_b,
                    const float* __restrict__ fc2_w, const float* __restrict__ fc2_b,
                    float* __restrict__ out) {
    __shared__ float p1[BB*100];
    int t = threadIdx.x;
    for (int idx = t; idx < BB*100; idx += 1024) {
        int b = idx / 100, j = idx % 100;
        float s = fc1_b[j];
        for (int q = 0; q < NT; ++q)
            s += p1p[(size_t)(b*NT + q)*100 + j];
        p1[idx] = fmaxf(s, 0.0f);
    }
    __syncthreads();
    if (t < BB*10) {
        int b = t / 10, j = t % 10;
        float acc = fc2_b[j];
        for (int k = 0; k < 100; ++k)
            acc += p1[b*100 + k] * fc2_w[j*100 + k];
        out[b*10 + j] = acc;
    }
}

extern "C" void kernel_launch(void* const* d_in, const int* in_sizes, int n_in,
                              void* d_out, int out_size, void* d_ws, size_t ws_size,
                              hipStream_t stream) {
    const float* input_tensor = (const float*)d_in[0];
    const float* topdown      = (const float*)d_in[1];
    const float* icw  = (const float*)d_in[2];
    const float* icb  = (const float*)d_in[3];
    const float* gates_w = (const float*)d_in[4];
    const float* gates_b = (const float*)d_in[5];
    const float* can_w   = (const float*)d_in[6];
    const float* can_b   = (const float*)d_in[7];
    const float* td_w0 = (const float*)d_in[8];
    const float* td_b0 = (const float*)d_in[9];
    const float* td_w1 = (const float*)d_in[10];
    const float* td_b1 = (const float*)d_in[11];
    const float* fc1_w = (const float*)d_in[12];
    const float* fc1_b = (const float*)d_in[13];
    const float* fc2_w = (const float*)d_in[14];
    const float* fc2_b = (const float*)d_in[15];
    float* out = (float*)d_out;

    float* ws   = (float*)d_ws;
    float* h12g = ws;                       // 100352 f
    float* p1p  = h12g + BB*HD*SP;          // 22400 f (224 blocks x 100)
    float* td0c = p1p + NBLK*100;           // 12544 f
    float* td1c = td0c + FEAT2;             // 12544 f
    unsigned* arrive  = (unsigned*)((char*)d_ws + (16u << 20));
    unsigned* release = arrive + NBLK*16;

    init_kernel<<<1, 256, 0, stream>>>(arrive, release);
    mega_kernel<<<NBLK, NTHR, 0, stream>>>(
        input_tensor, topdown, icw, icb, gates_w, gates_b, can_w, can_b,
        td_w0, td_b0, td_w1, td_b1, fc1_w,
        h12g, p1p, td0c, td1c, arrive, release);
    fc_tail_kernel<<<1, 1024, 0, stream>>>(p1p, fc1_b, fc2_w, fc2_b, out);
}

// Round 19
// 94.433 us; speedup vs baseline: 1.0807x; 1.0010x over previous
//
#include <hip/hip_runtime.h>
#include <cstddef>

#define HD 8
#define C2 16
#define HH 28
#define WW 28
#define BB 16
#define SP (HH*WW)           // 784
#define FEAT (HD*SP)         // 6272
#define FEAT2 (C2*SP)        // 12544

#define TILE_ROWS 2
#define NT (HH/TILE_ROWS)    // 14
#define NBLK (BB*NT)         // 224 blocks, one per (batch, row-tile)
#define NTHR 768             // 12 waves -> 3 waves/SIMD (measured best, round 16)

// LDS slab row extents (bases tied to r0)
#define X0_R 18   // x0  rows [r0-8, r0+9]
#define H00_R 14  // h00 rows [r0-6, r0+7]
#define H10_R 10  // h10 rows [r0-4, r0+5]
#define H11_R 6   // h11 rows [r0-2, r0+3]

__device__ __forceinline__ float sigf(float x) { return 1.0f / (1.0f + expf(-x)); }

union F4 { float4 v; float f[4]; };

struct SM {
    float gwt[C2*9][16];               // transposed gate weights [ic*9+k][oc]
    float cwt[C2*9][8];                // transposed cand weights [ic*9+k][oc]
    float icw2[27][8];                 // transposed input-conv weights (dedicated)
    float icb2[HD];
    float gb[C2];
    float cb[HD];
    float hc1[HD];
    float hc2[HD];
    float comb[C2][18][32];            // A-phase out; reused as fc1 scratch at tail
    union {
        float rh[HD][16][32];          // B-phase r*h, rows [ca-1, ca+M]
        float s_in[3][TILE_ROWS+18][32]; // raw input rows r0-9..r0+10 (staging)
    } u;
    float su[HD][14][32];              // sig(u-conv), rows [ca, ca+M-1]
    float x0e[HD][X0_R][32];
    float h00e[HD][H00_R][32];
    float h10e[HD][H10_R][32];
    float h11e[HD][H11_R][32];
};  // ~128.6 KB

// Grid barrier (FALLBACK PATH ONLY — never executed when sweep-0 node1/2 constants are 0).
// Measured: an in-kernel grid barrier costs ~60-70us on MI355X regardless of
// design (rounds 4-6, 14). Keep ALL happy-path sync at kernel boundaries.
__device__ __forceinline__ void gbar(unsigned* arrive, unsigned* release,
                                     int blk, unsigned ep) {
    __syncthreads();
    __threadfence();
    if (threadIdx.x == 0)
        __hip_atomic_store(&arrive[(size_t)blk * 16], ep,
                           __ATOMIC_RELEASE, __HIP_MEMORY_SCOPE_AGENT);
    if (blk == 0) {
        int t = threadIdx.x;
        if (t < NBLK) {
            while (__hip_atomic_load(&arrive[(size_t)t * 16],
                                     __ATOMIC_RELAXED, __HIP_MEMORY_SCOPE_AGENT) < ep)
                __builtin_amdgcn_s_sleep(32);
        }
        __syncthreads();
        if (t < NBLK)
            __hip_atomic_store(&release[(size_t)t * 16], ep,
                               __ATOMIC_RELEASE, __HIP_MEMORY_SCOPE_AGENT);
    } else {
        if (threadIdx.x == 0) {
            while (__hip_atomic_load(&release[(size_t)blk * 16],
                                     __ATOMIC_RELAXED, __HIP_MEMORY_SCOPE_AGENT) < ep)
                __builtin_amdgcn_s_sleep(32);
        }
    }
    __threadfence();
    __syncthreads();
}

// Stage node-n weights TRANSPOSED: gwt[ic*9+k][oc], cwt[ic*9+k][oc].
__device__ __forceinline__ void stage_node(SM& sm, int tid, int n,
                           const float* gates_w, const float* gates_b,
                           const float* can_w, const float* can_b) {
    for (int i = tid; i < C2*C2*9; i += NTHR) {
        int oc = i & 15, r = i >> 4;                   // r = ic*9+k
        sm.gwt[r][oc] = gates_w[n*C2*C2*9 + oc*C2*9 + r];
    }
    for (int i = tid; i < C2*9*8; i += NTHR) {
        int oc = i & 7, r = i >> 3;
        sm.cwt[r][oc] = can_w[n*HD*C2*9 + oc*C2*9 + r];
    }
    if (tid < C2) sm.gb[tid] = gates_b[n*C2 + tid];
    if (tid < HD) sm.cb[tid] = can_b[n*HD + tid];
    // consumer phase's preceding __syncthreads covers these writes
}

template<int XS>
__device__ __forceinline__ const float* xrow(SM& sm, int c, int ridx) {
    if constexpr (XS == 0) return &sm.x0e[c][ridx][0];
    else if constexpr (XS == 1) return &sm.h10e[c][ridx][0];
    else return &sm.h11e[c][ridx][0];
}

// Full ConvGRU cell in LDS. M compile-time.
// XS: x slab (0=x0e,1=h10e,2=h11e); HS: h (0=zero,1=h00e,2=hc1,3=hc2);
// OS: out (0=h00e,1=h10e,2=h11e,3=global h12g).
// HS==0 elision: comb[8..15]==0, r*h==0 -> no rh phase, 8-channel convs.
// PREA: comb[0..7] was pre-filled by an earlier phase (ends in __syncthreads)
// -> skip the A pass and its barrier entirely.
// NOTE: this cell form (merged B, su in LDS, 1-col/4-oc items) is the
// best-measured variant (rounds 12/15/16); rounds 13/14 variants regressed.
template<int M, int XS, int HS, int OS, bool PREA = false>
__device__ void cell(SM& sm, int tid, int bi, int r0, float xs,
                     const float* __restrict__ td, float* __restrict__ h12g) {
    constexpr int R1 = M + 4, R2 = M + 2;
    constexpr int NIC = (HS == 0) ? HD : C2;
    const int ca    = (OS == 0) ? r0-6 : (OS == 1) ? r0-4 : (OS == 2) ? r0-2 : r0;
    const int xbase = (XS == 0) ? r0-8 : (XS == 1) ? r0-4 : r0-2;
    const int hbase = r0 - 6;                          // HS==1 only

    // ---- A: comb = (c<8 ? xs*x : h) * sig(td), float4 over cols ----
    if constexpr (!PREA) {
        for (int i = tid; i < NIC*R1*8; i += NTHR) {
            int ci4 = i & 7, rr = (i >> 3) % R1, c = i / (8*R1);
            int row = ca - 2 + rr;
            F4 v; v.f[0] = v.f[1] = v.f[2] = v.f[3] = 0.0f;
            if (row >= 0 && row < HH) {
                F4 base;
                if (c < HD) {
                    base.v = *(const float4*)(xrow<XS>(sm, c, row - xbase) + ci4*4);
                    #pragma unroll
                    for (int e = 0; e < 4; ++e) base.f[e] *= xs;
                } else {
                    if constexpr (HS == 1)
                        base.v = *(const float4*)(&sm.h00e[c-HD][row - hbase][ci4*4]);
                    else if constexpr (HS == 2) {
                        float h = sm.hc1[c-HD];
                        base.f[0] = base.f[1] = base.f[2] = base.f[3] = h;
                    } else {
                        float h = sm.hc2[c-HD];
                        base.f[0] = base.f[1] = base.f[2] = base.f[3] = h;
                    }
                }
                const float* tdr = td + c*SP + row*WW;
                #pragma unroll
                for (int e = 0; e < 4; ++e) {
                    int col = ci4*4 + e - 2;
                    if (col >= 0 && col < WW)
                        v.f[e] = base.f[e] * sigf(tdr[col]);
                }
            }
            *(float4*)&sm.comb[c][rr][ci4*4] = v.v;
        }
        __syncthreads();
    }

    // ---- B: rh rows [ca-1,ca+M] (HS!=0) MERGED WITH u-conv -> su rows [ca,ca+M-1] ----
    constexpr int itemsU = 2*M*32;
    if constexpr (HS != 0) {
        constexpr int itemsB = 2*R2*32;
        for (int i = tid; i < itemsB + itemsU; i += NTHR) {
            if (i < itemsB) {
                int ci = i & 31, rr = (i >> 5) % R2, g = i / (32*R2);
                int row = ca - 1 + rr, col = ci - 2;
                bool inb = (col >= 0 && col < WW && row >= 0 && row < HH);
                float a0 = sm.gb[g*4+0], a1 = sm.gb[g*4+1],
                      a2 = sm.gb[g*4+2], a3 = sm.gb[g*4+3];
                if (inb) {
                    #pragma unroll 2
                    for (int ic = 0; ic < C2; ++ic) {
                        const float* wb = &sm.gwt[ic*9][g*4];
                        #pragma unroll
                        for (int dy = 0; dy < 3; ++dy)
                            #pragma unroll
                            for (int dx = 0; dx < 3; ++dx) {
                                float cvv = sm.comb[ic][rr+dy][ci-1+dx];
                                F4 w; w.v = *(const float4*)(wb + (dy*3+dx)*16);
                                a0 += cvv*w.f[0]; a1 += cvv*w.f[1];
                                a2 += cvv*w.f[2]; a3 += cvv*w.f[3];
                            }
                    }
                }
                float av[4] = {a0, a1, a2, a3};
                #pragma unroll
                for (int o = 0; o < 4; ++o) {
                    int c = g*4 + o;
                    float v = 0.0f;
                    if (inb) {
                        float hv;
                        if constexpr (HS == 1) hv = sm.h00e[c][row - hbase][ci];
                        else if constexpr (HS == 2) hv = sm.hc1[c];
                        else hv = sm.hc2[c];
                        v = sigf(av[o]) * hv;
                    }
                    sm.u.rh[c][rr][ci] = v;
                }
            } else {
                int j = i - itemsB;
                int ci = j & 31, rr = (j >> 5) % M, g = j / (32*M);
                int row = ca + rr, col = ci - 2;
                bool inb = (col >= 0 && col < WW && row >= 0 && row < HH);
                float a0 = sm.gb[HD+g*4+0], a1 = sm.gb[HD+g*4+1],
                      a2 = sm.gb[HD+g*4+2], a3 = sm.gb[HD+g*4+3];
                if (inb) {
                    #pragma unroll 2
                    for (int ic = 0; ic < C2; ++ic) {
                        const float* wb = &sm.gwt[ic*9][HD + g*4];
                        #pragma unroll
                        for (int dy = 0; dy < 3; ++dy)
                            #pragma unroll
                            for (int dx = 0; dx < 3; ++dx) {
                                float cvv = sm.comb[ic][rr+1+dy][ci-1+dx];
                                F4 w; w.v = *(const float4*)(wb + (dy*3+dx)*16);
                                a0 += cvv*w.f[0]; a1 += cvv*w.f[1];
                                a2 += cvv*w.f[2]; a3 += cvv*w.f[3];
                            }
                    }
                }
                float av[4] = {a0, a1, a2, a3};
                #pragma unroll
                for (int o = 0; o < 4; ++o)
                    sm.su[g*4+o][rr][ci] = sigf(av[o]);
            }
        }
    } else {
        for (int i = tid; i < itemsU; i += NTHR) {
            int ci = i & 31, rr = (i >> 5) % M, g = i / (32*M);
            int row = ca + rr, col = ci - 2;
            bool inb = (col >= 0 && col < WW && row >= 0 && row < HH);
            float a0 = sm.gb[HD+g*4+0], a1 = sm.gb[HD+g*4+1],
                  a2 = sm.gb[HD+g*4+2], a3 = sm.gb[HD+g*4+3];
            if (inb) {
                #pragma unroll 2
                for (int ic = 0; ic < HD; ++ic) {
                    const float* wb = &sm.gwt[ic*9][HD + g*4];
                    #pragma unroll
                    for (int dy = 0; dy < 3; ++dy)
                        #pragma unroll
                        for (int dx = 0; dx < 3; ++dx) {
                            float cvv = sm.comb[ic][rr+1+dy][ci-1+dx];
                            F4 w; w.v = *(const float4*)(wb + (dy*3+dx)*16);
                            a0 += cvv*w.f[0]; a1 += cvv*w.f[1];
                            a2 += cvv*w.f[2]; a3 += cvv*w.f[3];
                        }
                }
            }
            float av[4] = {a0, a1, a2, a3};
            #pragma unroll
            for (int o = 0; o < 4; ++o)
                sm.su[g*4+o][rr][ci] = sigf(av[o]);
        }
    }
    __syncthreads();

    // ---- C: cand conv + blend, rows [ca, ca+M-1] ----
    for (int i = tid; i < 2*M*32; i += NTHR) {
        int ci = i & 31, rr = (i >> 5) % M, g = i / (32*M);
        int row = ca + rr, col = ci - 2;
        bool inb = (col >= 0 && col < WW && row >= 0 && row < HH);
        float a0 = sm.cb[g*4+0], a1 = sm.cb[g*4+1],
              a2 = sm.cb[g*4+2], a3 = sm.cb[g*4+3];
        if (inb) {
            #pragma unroll 2
            for (int ic = 0; ic < HD; ++ic) {
                const float* wb = &sm.cwt[ic*9][g*4];
                #pragma unroll
                for (int dy = 0; dy < 3; ++dy) {
                    const float* xr = xrow<XS>(sm, ic, (row - 1 + dy) - xbase);
                    #pragma unroll
                    for (int dx = 0; dx < 3; ++dx) {
                        float civ = xs * xr[ci-1+dx];
                        F4 w; w.v = *(const float4*)(wb + (dy*3+dx)*8);
                        a0 += civ*w.f[0]; a1 += civ*w.f[1];
                        a2 += civ*w.f[2]; a3 += civ*w.f[3];
                    }
                }
            }
            if constexpr (HS != 0) {
                #pragma unroll 2
                for (int ic = HD; ic < C2; ++ic) {
                    const float* wb = &sm.cwt[ic*9][g*4];
                    #pragma unroll
                    for (int dy = 0; dy < 3; ++dy)
                        #pragma unroll
                        for (int dx = 0; dx < 3; ++dx) {
                            float civ = sm.u.rh[ic-HD][rr+dy][ci-1+dx];
                            F4 w; w.v = *(const float4*)(wb + (dy*3+dx)*8);
                            a0 += civ*w.f[0]; a1 += civ*w.f[1];
                            a2 += civ*w.f[2]; a3 += civ*w.f[3];
                        }
                }
            }
        }
        float av[4] = {a0, a1, a2, a3};
        #pragma unroll
        for (int o = 0; o < 4; ++o) {
            int c = g*4 + o;
            float outv = 0.0f;
            if (inb) {
                float uu = sm.su[c][rr][ci];
                float cand = tanhf(av[o]);
                float hv;
                if constexpr (HS == 1) hv = sm.h00e[c][row - hbase][ci];
                else if constexpr (HS == 2) hv = sm.hc1[c];
                else if constexpr (HS == 3) hv = sm.hc2[c];
                else hv = 0.0f;
                outv = (1.0f - uu) * hv + uu * cand;
            }
            if constexpr (OS == 0) sm.h00e[c][row - (r0-6)][ci] = outv;
            else if constexpr (OS == 1) sm.h10e[c][row - (r0-4)][ci] = outv;
            else if constexpr (OS == 2) sm.h11e[c][row - (r0-2)][ci] = outv;
            else {
                if (inb)
                    h12g[((size_t)bi*HD + c)*SP + row*WW + col] = outv;
            }
        }
    }
    __syncthreads();
}

__global__ void init_kernel(unsigned* arrive, unsigned* release) {
    int t = threadIdx.x;
    for (int i = t; i < NBLK*16; i += 256) { arrive[i] = 0u; release[i] = 0u; }
}

// (768, 3): 3 waves/SIMD (measured best); VGPR budget ~170/wave; LDS ~129 KB
// -> 1 block/CU.
__global__ __launch_bounds__(NTHR, 3)
void mega_kernel(const float* __restrict__ input_tensor, const float* __restrict__ topdown,
                 const float* __restrict__ icw, const float* __restrict__ icb,
                 const float* __restrict__ gates_w, const float* __restrict__ gates_b,
                 const float* __restrict__ can_w, const float* __restrict__ can_b,
                 const float* __restrict__ td_w0, const float* __restrict__ td_b0,
                 const float* __restrict__ td_w1, const float* __restrict__ td_b1,
                 const float* __restrict__ fc1_w,
                 float* __restrict__ h12g, float* __restrict__ p1p,
                 float* __restrict__ td0c, float* __restrict__ td1c,
                 unsigned* arrive, unsigned* release)
{
    const int tid = threadIdx.x;
    const int blk = blockIdx.x;
    const int bi  = blk / NT;
    const int r0  = (blk % NT) * TILE_ROWS;

    __shared__ SM sm;

    // Sweep-0 node1/2 outputs are per-channel constants (x=0,h=0 => comb==0).
    if (tid < HD) {
        sm.hc1[tid] = sigf(gates_b[1*C2 + HD + tid]) * tanhf(can_b[1*HD + tid]);
        sm.hc2[tid] = sigf(gates_b[2*C2 + HD + tid]) * tanhf(can_b[2*HD + tid]);
    }
    bool f0 = false, f1 = false;
    for (int c = 0; c < HD; ++c) {
        f0 |= (sigf(gates_b[1*C2 + HD + c]) * tanhf(can_b[1*HD + c])) != 0.0f;
        f1 |= (sigf(gates_b[2*C2 + HD + c]) * tanhf(can_b[2*HD + c])) != 0.0f;
    }

    // ---- staging: raw input tile (rows r0-9..r0+10), input-conv weights
    //      (dedicated icw2/icb2), AND node-0 weights (disjoint arrays) ----
    for (int i = tid; i < 3*(TILE_ROWS+18)*32; i += NTHR) {
        int ci = i & 31, rr = (i >> 5) % (TILE_ROWS+18), c = i / (32*(TILE_ROWS+18));
        int row = r0 - 9 + rr, col = ci - 2;
        float v = 0.0f;
        if (row >= 0 && row < HH && col >= 0 && col < WW)
            v = input_tensor[((size_t)bi*3 + c)*SP + row*WW + col];
        sm.u.s_in[c][rr][ci] = v;
    }
    for (int i = tid; i < 3*9*8; i += NTHR) {          // transposed input-conv w
        int oc = i & 7, r = i >> 3;                    // r = ic*9+k < 27
        sm.icw2[r][oc] = icw[oc*27 + r];
    }
    if (tid < HD) sm.icb2[tid] = icb[tid];
    stage_node(sm, tid, 0, gates_w, gates_b, can_w, can_b);
    __syncthreads();

    // ---- x0e + h00's comb fused: rows [r0-8, r0+9]; item=(row,col) ----
    // comb row base equals x0 base (ca-2 = r0-8 for M=14), and h00's td is
    // STRUCTURALLY td_b0 (sweep-0 node-0 td-proj input is zero) -> comb can
    // be produced here from the same acc values (bit-exact vs the A pass).
    for (int i = tid; i < X0_R*32; i += NTHR) {
        int ci = i & 31, rr = i >> 5;
        int row = r0 - 8 + rr, col = ci - 2;
        float acc[8];
        bool inb = (row >= 0 && row < HH && col >= 0 && col < WW);
        if (inb) {
            #pragma unroll
            for (int o = 0; o < 8; ++o) acc[o] = sm.icb2[o];
            for (int ic = 0; ic < 3; ++ic)
                #pragma unroll
                for (int dy = 0; dy < 3; ++dy)
                    #pragma unroll
                    for (int dx = 0; dx < 3; ++dx) {
                        float a = sm.u.s_in[ic][rr+dy][ci-1+dx];
                        F4 w0, w1;
                        w0.v = *(const float4*)&sm.icw2[ic*9+dy*3+dx][0];
                        w1.v = *(const float4*)&sm.icw2[ic*9+dy*3+dx][4];
                        acc[0] += a*w0.f[0]; acc[1] += a*w0.f[1];
                        acc[2] += a*w0.f[2]; acc[3] += a*w0.f[3];
                        acc[4] += a*w1.f[0]; acc[5] += a*w1.f[1];
                        acc[6] += a*w1.f[2]; acc[7] += a*w1.f[3];
                    }
        } else {
            #pragma unroll
            for (int o = 0; o < 8; ++o) acc[o] = 0.0f;
        }
        #pragma unroll
        for (int o = 0; o < 8; ++o) {
            sm.x0e[o][rr][ci] = acc[o];
            float cmb = 0.0f;
            if (inb)
                cmb = acc[o] * sigf(td_b0[o*SP + row*WW + col]);
            sm.comb[o][rr][ci] = cmb;
        }
    }
    __syncthreads();   // x0e + comb ready; node-0 weights (staged earlier) covered

    // ---- h00: sweep-0 node 0 (h=0, comb pre-filled), rows [r0-6, r0+7] ----
    cell<14, 0, 0, 0, true>(sm, tid, bi, r0, 1.0f, td_b0, nullptr);

    // ---- fallback: real td projections (h01/h02 constants nonzero) ----
    if (f0 | f1) {
        if (f0) {
            for (int j = blk*NTHR + tid; j < FEAT2; j += NBLK*NTHR) {
                float s = td_b0[j];
                const float* wr = td_w0 + (size_t)j * FEAT;
                for (int c = 0; c < HD; ++c) {
                    float hcv = sm.hc1[c];
                    if (hcv != 0.0f) {
                        float ss = 0.0f;
                        for (int p = 0; p < SP; ++p) ss += wr[c*SP + p];
                        s += 0.6f * hcv * ss;
                    }
                }
                td0c[j] = s;
            }
        }
        if (f1) {
            for (int j = blk*NTHR + tid; j < FEAT2; j += NBLK*NTHR) {
                float s = td_b1[j];
                const float* wr = td_w1 + (size_t)j * FEAT;
                for (int c = 0; c < HD; ++c) {
                    float hcv = sm.hc2[c];
                    if (hcv != 0.0f) {
                        float ss = 0.0f;
                        for (int p = 0; p < SP; ++p) ss += wr[c*SP + p];
                        s += 0.5f * hcv * ss;
                    }
                }
                td1c[j] = s;
            }
        }
        gbar(arrive, release, blk, 1u);   // uniform branch: all blocks take it
    }
    const float* td0v = f0 ? td0c : td_b0;
    const float* td1v = f1 ? td1c : td_b1;

    // ---- h10: sweep-1 node 0 (weights resident), rows [r0-4, r0+5] ----
    cell<10, 0, 1, 1>(sm, tid, bi, r0, 1.0f, td0v, nullptr);

    // ---- h11: sweep-1 node 1 (x=0.8*h10, h=hc1), rows [r0-2, r0+3] ----
    stage_node(sm, tid, 1, gates_w, gates_b, can_w, can_b);
    cell<6, 1, 2, 2>(sm, tid, bi, r0, 0.8f, td1v, nullptr);

    // ---- h12: sweep-1 node 2 (x=0.7*h11, h=hc2, td external), rows [r0, r0+1] ----
    stage_node(sm, tid, 2, gates_w, gates_b, can_w, can_b);
    cell<2, 2, 3, 3>(sm, tid, bi, r0, 0.7f, topdown + (size_t)bi*FEAT2, h12g);

    // ---- fc1 partials (fused tail): this block owns batch bi's k-slice
    // rows r0..r0+1 (448 k's). No extra sync needed: we read only OUR OWN
    // h12 writes (drained by the cell's final __syncthreads, L2-coherent on
    // the same CU). Deterministic: fixed part decomposition + fixed sum order.
    {
        float* scratch = &sm.comb[0][0][0];   // comb free after last cell
        if (tid < 400) {
            int j = tid >> 2, p = tid & 3;    // j=0..99, 4 parts x 112 k's
            float acc = 0.0f;
            for (int s = 0; s < 112; ++s) {
                int kl  = p*112 + s;          // 0..447: c-major, row, col
                int c   = kl / 56;
                int rem = kl % 56;
                int rr  = rem / 28, col = rem % 28;
                int k   = c*SP + (r0 + rr)*WW + col;
                float v = h12g[(size_t)bi*FEAT + k];
                acc += fmaxf(v, 0.0f) * fc1_w[(size_t)j*FEAT + k];
            }
            scratch[j*4 + p] = acc;
        }
        __syncthreads();
        if (tid < 100) {
            float s = scratch[tid*4+0] + scratch[tid*4+1]
                    + scratch[tid*4+2] + scratch[tid*4+3];
            p1p[(size_t)blk*100 + tid] = s;
        }
    }
}

// Combine fc1 partials (fixed tile order) + bias + relu, then fc2. 1 block.
__global__ __launch_bounds__(1024)
void fc_tail_kernel(const float* __restrict__ p1p, const float* __restrict__ fc1_b,
                    const float* __restrict__ fc2_w, const float* __restrict__ fc2_b,
                    float* __restrict__ out) {
    __shared__ float p1[BB*100];
    int t = threadIdx.x;
    for (int idx = t; idx < BB*100; idx += 1024) {
        int b = idx / 100, j = idx % 100;
        float s = fc1_b[j];
        for (int q = 0; q < NT; ++q)
            s += p1p[(size_t)(b*NT + q)*100 + j];
        p1[idx] = fmaxf(s, 0.0f);
    }
    __syncthreads();
    if (t < BB*10) {
        int b = t / 10, j = t % 10;
        float acc = fc2_b[j];
        for (int k = 0; k < 100; ++k)
            acc += p1[b*100 + k] * fc2_w[j*100 + k];
        out[b*10 + j] = acc;
    }
}

extern "C" void kernel_launch(void* const* d_in, const int* in_sizes, int n_in,
                              void* d_out, int out_size, void* d_ws, size_t ws_size,
                              hipStream_t stream) {
    const float* input_tensor = (const float*)d_in[0];
    const float* topdown      = (const float*)d_in[1];
    const float* icw  = (const float*)d_in[2];
    const float* icb  = (const float*)d_in[3];
    const float* gates_w = (const float*)d_in[4];
    const float* gates_b = (const float*)d_in[5];
    const float* can_w   = (const float*)d_in[6];
    const float* can_b   = (const float*)d_in[7];
    const float* td_w0 = (const float*)d_in[8];
    const float* td_b0 = (const float*)d_in[9];
    const float* td_w1 = (const float*)d_in[10];
    const float* td_b1 = (const float*)d_in[11];
    const float* fc1_w = (const float*)d_in[12];
    const float* fc1_b = (const float*)d_in[13];
    const float* fc2_w = (const float*)d_in[14];
    const float* fc2_b = (const float*)d_in[15];
    float* out = (float*)d_out;

    float* ws   = (float*)d_ws;
    float* h12g = ws;                       // 100352 f
    float* p1p  = h12g + BB*HD*SP;          // 22400 f (224 blocks x 100)
    float* td0c = p1p + NBLK*100;           // 12544 f
    float* td1c = td0c + FEAT2;             // 12544 f
    unsigned* arrive  = (unsigned*)((char*)d_ws + (16u << 20));
    unsigned* release = arrive + NBLK*16;

    init_kernel<<<1, 256, 0, stream>>>(arrive, release);
    mega_kernel<<<NBLK, NTHR, 0, stream>>>(
        input_tensor, topdown, icw, icb, gates_w, gates_b, can_w, can_b,
        td_w0, td_b0, td_w1, td_b1, fc1_w,
        h12g, p1p, td0c, td1c, arrive, release);
    fc_tail_kernel<<<1, 1024, 0, stream>>>(p1p, fc1_b, fc2_w, fc2_b, out);
}